// Round 9
// baseline (133.395 us; speedup 1.0000x reference)
//
#include <hip/hip_runtime.h>
#include <hip/hip_bf16.h>
#include <cmath>

#define DMODEL 1024
#define NH 16
#define DH 64
#define SEQ 2048
#define BATCH 2

typedef __attribute__((ext_vector_type(8))) short bf16x8;
typedef __attribute__((ext_vector_type(4))) float f32x4;
typedef __attribute__((ext_vector_type(4))) unsigned int u32x4;
typedef __attribute__((ext_vector_type(8))) unsigned short u16x8;

__device__ __forceinline__ unsigned short f2bf(float f) {
    unsigned int u = __builtin_bit_cast(unsigned int, f);
    u += 0x7fffu + ((u >> 16) & 1u);
    return (unsigned short)(u >> 16);
}
__device__ __forceinline__ float bf2f(unsigned short s) {
    unsigned int u = ((unsigned int)s) << 16;
    return __builtin_bit_cast(float, u);
}
// 2^x in one v_exp_f32
__device__ __forceinline__ float exp2_fast(float x) {
    float r;
    asm("v_exp_f32 %0, %1" : "=v"(r) : "v"(x));
    return r;
}

// ---------------------------------------------------------------------------
// fp32 -> bf16 cast of x, w_qkv, w_out in ONE kernel. 8 elems/thread.
// ---------------------------------------------------------------------------
__global__ __launch_bounds__(256)
void cast_all(const float* __restrict__ x, const float* __restrict__ wq,
              const float* __restrict__ wo, unsigned short* __restrict__ xb,
              unsigned short* __restrict__ wqb, unsigned short* __restrict__ wob)
{
    const int i = blockIdx.x * 256 + threadIdx.x;
    const float* src; unsigned short* dst; int off;
    if (i < 524288)      { src = x;  dst = xb;  off = i; }
    else if (i < 917504) { src = wq; dst = wqb; off = i - 524288; }
    else                 { src = wo; dst = wob; off = i - 917504; }
    const float4 a = *(const float4*)(src + (size_t)off * 8);
    const float4 b = *(const float4*)(src + (size_t)off * 8 + 4);
    u16x8 o;
    o[0] = f2bf(a.x); o[1] = f2bf(a.y); o[2] = f2bf(a.z); o[3] = f2bf(a.w);
    o[4] = f2bf(b.x); o[5] = f2bf(b.y); o[6] = f2bf(b.z); o[7] = f2bf(b.w);
    *(u16x8*)(dst + (size_t)off * 8) = o;
}

// ---------------------------------------------------------------------------
// bf16 MFMA GEMM (unchanged): C[M,N] = A[M,K] * B[N,K]^T, K=1024, f32 accum.
// EPI==0 (BM=128): fused-RoPE epilogue -> q,k [B][H][S][64], vt [B][H][64][S].
// EPI==1: plain fp32 write.
// ---------------------------------------------------------------------------
template<int BM, int EPI>
__global__ __launch_bounds__(256)
void gemm_bf16(const unsigned short* __restrict__ A,
               const unsigned short* __restrict__ B,
               float* __restrict__ oc, unsigned short* __restrict__ oq,
               unsigned short* __restrict__ ok, unsigned short* __restrict__ ovt,
               int M, int N)
{
    constexpr int K = 1024;
    constexpr int BK = 32;
    constexpr int NT = K / BK;
    constexpr int FM = BM / 32;
    __shared__ unsigned short As[2][BM * BK];
    __shared__ unsigned short Bs[2][128 * BK];

    const int t  = threadIdx.x;
    const int l  = t & 63;
    const int w  = t >> 6;
    const int g  = l >> 4;
    const int ln = l & 15;
    const int wr = w >> 1, wc = w & 1;
    const int m0 = blockIdx.y * BM;
    const int n0 = blockIdx.x * 128;

    auto stage = [&](int kt, int bufi) {
        #pragma unroll
        for (int i = 0; i < BM / 64; ++i) {
            const int n = i * 256 + t;
            const int r = n >> 2, slot = n & 3;
            const int kk = kt * BK + ((slot ^ ((r >> 1) & 3)) * 8);
            const unsigned short* ga = A + (size_t)(m0 + r) * K + kk;
            __builtin_amdgcn_global_load_lds(
                (const __attribute__((address_space(1))) unsigned int*)ga,
                (__attribute__((address_space(3))) unsigned int*)&As[bufi][n * 8], 16, 0, 0);
        }
        #pragma unroll
        for (int i = 0; i < 2; ++i) {
            const int n = i * 256 + t;
            const int r = n >> 2, slot = n & 3;
            const int kk = kt * BK + ((slot ^ ((r >> 1) & 3)) * 8);
            const unsigned short* gb = B + (size_t)(n0 + r) * K + kk;
            __builtin_amdgcn_global_load_lds(
                (const __attribute__((address_space(1))) unsigned int*)gb,
                (__attribute__((address_space(3))) unsigned int*)&Bs[bufi][n * 8], 16, 0, 0);
        }
    };

    f32x4 acc[FM][4];
    #pragma unroll
    for (int i = 0; i < FM; ++i)
        #pragma unroll
        for (int j = 0; j < 4; ++j) acc[i][j] = (f32x4){0.f, 0.f, 0.f, 0.f};

    const int swz = (g ^ ((ln >> 1) & 3)) << 4;

    stage(0, 0);
    for (int kt = 0; kt < NT; ++kt) {
        __syncthreads();
        if (kt + 1 < NT) stage(kt + 1, (kt + 1) & 1);
        const char* as = (const char*)As[kt & 1];
        const char* bs = (const char*)Bs[kt & 1];
        bf16x8 af[FM], bfr[4];
        #pragma unroll
        for (int fm = 0; fm < FM; ++fm)
            af[fm] = *(const bf16x8*)(as + (wr * (BM / 2) + fm * 16 + ln) * 64 + swz);
        #pragma unroll
        for (int fn = 0; fn < 4; ++fn)
            bfr[fn] = *(const bf16x8*)(bs + (wc * 64 + fn * 16 + ln) * 64 + swz);
        #pragma unroll
        for (int fm = 0; fm < FM; ++fm)
            #pragma unroll
            for (int fn = 0; fn < 4; ++fn)
                acc[fm][fn] = __builtin_amdgcn_mfma_f32_16x16x32_bf16(
                    af[fm], bfr[fn], acc[fm][fn], 0, 0, 0);
    }

    const int rowbase = m0 + wr * (BM / 2);
    const int colbase = n0 + wc * 64;
    if (EPI == 1) {
        #pragma unroll
        for (int fm = 0; fm < FM; ++fm)
            #pragma unroll
            for (int fn = 0; fn < 4; ++fn)
                #pragma unroll
                for (int rr = 0; rr < 4; ++rr) {
                    const int row = rowbase + fm * 16 + g * 4 + rr;
                    oc[(size_t)row * N + colbase + fn * 16 + ln] = acc[fm][fn][rr];
                }
    } else {
        const int which = colbase >> 10;          // 0=q 1=k 2=v
        const int h = (colbase >> 6) & (NH - 1);
        if (which < 2) {
            // fused RoPE; q also scaled by log2e/8 (scores in log2 domain).
            unsigned short* dst = which == 0 ? oq : ok;
            const float scale = which == 0 ? 0.18033688011112042f : 1.f;
            const float cexp = -13.287712379549449f / 32.f;   // -log2(1e4)/32
            const float if0 = exp2f((float)ln * cexp);
            const float if1 = exp2f((float)(16 + ln) * cexp);
            #pragma unroll
            for (int fm = 0; fm < FM; ++fm)
                #pragma unroll
                for (int rr = 0; rr < 4; ++rr) {
                    const int row = rowbase + fm * 16 + g * 4 + rr;
                    const int b = row >> 11, s = row & (SEQ - 1);
                    float s0, c0, s1, c1;
                    __sincosf((float)s * if0, &s0, &c0);
                    __sincosf((float)s * if1, &s1, &c1);
                    const float x0 = acc[fm][0][rr], x1 = acc[fm][1][rr];
                    const float x2 = acc[fm][2][rr], x3 = acc[fm][3][rr];
                    const size_t base = (((size_t)b * NH + h) * SEQ + s) * DH;
                    dst[base + ln]      = f2bf((x0 * c0 - x2 * s0) * scale);
                    dst[base + 16 + ln] = f2bf((x1 * c1 - x3 * s1) * scale);
                    dst[base + 32 + ln] = f2bf((x2 * c0 + x0 * s0) * scale);
                    dst[base + 48 + ln] = f2bf((x3 * c1 + x1 * s1) * scale);
                }
        } else {
            #pragma unroll
            for (int fm = 0; fm < FM; ++fm)
                #pragma unroll
                for (int fn = 0; fn < 4; ++fn) {
                    const int row = rowbase + fm * 16 + g * 4;
                    const int b = row >> 11, s = row & (SEQ - 1);
                    const int d = fn * 16 + ln;
                    ushort4 pk;
                    pk.x = f2bf(acc[fm][fn][0]); pk.y = f2bf(acc[fm][fn][1]);
                    pk.z = f2bf(acc[fm][fn][2]); pk.w = f2bf(acc[fm][fn][3]);
                    *(ushort4*)&ovt[(((size_t)b * NH + h) * DH + d) * SEQ + s] = pk;
                }
        }
    }
}

// ---------------------------------------------------------------------------
// Flash attention, bf16 MFMA, causal, causal-fold paired, SPLIT-K by kt
// parity (blockIdx.z = z handles kt = z, z+2, ...). Static-max softmax makes
// partials trivially combinable: per-z unnormalized O (bf16) and l (f32)
// partials just add. In-register P (permuted K-row reads), no P LDS.
// ---------------------------------------------------------------------------
__global__ __launch_bounds__(256)
void attn_mfma(const unsigned short* __restrict__ q,
               const unsigned short* __restrict__ k,
               const unsigned short* __restrict__ vt,
               unsigned short* __restrict__ O0, unsigned short* __restrict__ O1,
               float* __restrict__ l0, float* __restrict__ l1)
{
    __shared__ unsigned short Ks[2][64 * 64];
    __shared__ unsigned short Vs[2][64 * 64];

    const int t  = threadIdx.x;
    const int l  = t & 63;
    const int w  = t >> 6;
    const int g  = l >> 4;
    const int ln = l & 15;
    const int pi = blockIdx.x;            // 0..15
    const int qtA = pi, qtB = 31 - pi;
    const int bh = blockIdx.y;
    const int z  = blockIdx.z;            // kt parity
    unsigned short* Op = z ? O1 : O0;
    float* lp = z ? l1 : l0;
    const size_t bqk = (size_t)bh * SEQ * DH;
    const size_t bv  = (size_t)bh * DH * SEQ;

    bf16x8 qfA0, qfA1, qfB0, qfB1;
    {
        const unsigned short* qa = q + bqk + (size_t)(qtA * 64 + w * 16 + ln) * DH + g * 8;
        qfA0 = *(const bf16x8*)qa;  qfA1 = *(const bf16x8*)(qa + 32);
        const unsigned short* qb2 = q + bqk + (size_t)(qtB * 64 + w * 16 + ln) * DH + g * 8;
        qfB0 = *(const bf16x8*)qb2; qfB1 = *(const bf16x8*)(qb2 + 32);
    }

    f32x4 aoA[4], aoB[4];
    #pragma unroll
    for (int i = 0; i < 4; ++i) {
        aoA[i] = (f32x4){0.f, 0.f, 0.f, 0.f};
        aoB[i] = (f32x4){0.f, 0.f, 0.f, 0.f};
    }
    float lA = 0.f, lB = 0.f;   // per-lane partial denominators

    auto stage = [&](int kt, int bufi) {
        #pragma unroll
        for (int rr = 0; rr < 2; ++rr) {
            const int id  = rr * 256 + t;           // 0..511
            const int row = id >> 3, sl = id & 7;
            const int sg  = (row & 3) | (((row >> 3) & 1) << 2);
            const int slg = (sl ^ sg) * 8;
            const unsigned short* gk = k  + bqk + (size_t)(kt * 64 + row) * DH + slg;
            const unsigned short* gv = vt + bv  + (size_t)row * SEQ + kt * 64 + slg;
            __builtin_amdgcn_global_load_lds(
                (const __attribute__((address_space(1))) unsigned int*)gk,
                (__attribute__((address_space(3))) unsigned int*)&Ks[bufi][id * 8], 16, 0, 0);
            __builtin_amdgcn_global_load_lds(
                (const __attribute__((address_space(1))) unsigned int*)gv,
                (__attribute__((address_space(3))) unsigned int*)&Vs[bufi][id * 8], 16, 0, 0);
        }
    };

    const int rowoffK = ((ln >> 2) * 8 + (ln & 3)) * 128;
    const int sK = (ln & 3) | (((ln >> 2) & 1) << 2);
    const int slotK0 = ((g ^ sK) << 4);
    const int slotK1 = (((g + 4) ^ sK) << 4);
    const int sV = (ln & 3) | (((ln >> 3) & 1) << 2);

    auto softmax_tile = [&](f32x4* s, float& l_, bf16x8* pf) {
        const float M2 = 28.853900817779268f;     // 20 * log2(e)
        float rs = 0.f;
        unsigned int dw[8];
        #pragma unroll
        for (int nb = 0; nb < 4; ++nb) {
            float e[4];
            #pragma unroll
            for (int r = 0; r < 4; ++r)
                e[r] = exp2_fast(s[nb][r] - M2);
            rs += (e[0] + e[1]) + (e[2] + e[3]);
            dw[nb * 2] = __builtin_amdgcn_perm(
                __builtin_bit_cast(unsigned int, e[1]),
                __builtin_bit_cast(unsigned int, e[0]), 0x07060302u);
            dw[nb * 2 + 1] = __builtin_amdgcn_perm(
                __builtin_bit_cast(unsigned int, e[3]),
                __builtin_bit_cast(unsigned int, e[2]), 0x07060302u);
        }
        l_ += rs;
        pf[0] = __builtin_bit_cast(bf16x8, (u32x4){dw[0], dw[1], dw[2], dw[3]});
        pf[1] = __builtin_bit_cast(bf16x8, (u32x4){dw[4], dw[5], dw[6], dw[7]});
    };

    int buf = 0;
    stage(z, 0);
    for (int kt = z; kt <= qtB; kt += 2) {
        __syncthreads();                      // buf staged & safe
        if (kt + 2 <= qtB) stage(kt + 2, buf ^ 1);
        const bool actA = (kt <= qtA);
        const char* kb = (const char*)Ks[buf];
        const char* vb = (const char*)Vs[buf];

        f32x4 sA[4], sB[4];
        #pragma unroll
        for (int nb = 0; nb < 4; ++nb) {
            sA[nb] = (f32x4){0.f, 0.f, 0.f, 0.f};
            sB[nb] = (f32x4){0.f, 0.f, 0.f, 0.f};
        }
        __builtin_amdgcn_s_setprio(1);
        #pragma unroll
        for (int nb = 0; nb < 4; ++nb) {
            const char* kr = kb + ((nb >> 1) * 32 + (nb & 1) * 4) * 128 + rowoffK;
            bf16x8 kf0 = *(const bf16x8*)(kr + slotK0);
            bf16x8 kf1 = *(const bf16x8*)(kr + slotK1);
            sB[nb] = __builtin_amdgcn_mfma_f32_16x16x32_bf16(kf0, qfB0, sB[nb], 0, 0, 0);
            sB[nb] = __builtin_amdgcn_mfma_f32_16x16x32_bf16(kf1, qfB1, sB[nb], 0, 0, 0);
            if (actA) {
                sA[nb] = __builtin_amdgcn_mfma_f32_16x16x32_bf16(kf0, qfA0, sA[nb], 0, 0, 0);
                sA[nb] = __builtin_amdgcn_mfma_f32_16x16x32_bf16(kf1, qfA1, sA[nb], 0, 0, 0);
            }
        }
        __builtin_amdgcn_s_setprio(0);

        // causal mask; score reg (nb,r) holds key = (nb>>1)*32+g*8+(nb&1)*4+r
        if (kt == qtB) {
            #pragma unroll
            for (int nb = 0; nb < 4; ++nb)
                #pragma unroll
                for (int r = 0; r < 4; ++r)
                    if ((nb >> 1) * 32 + g * 8 + (nb & 1) * 4 + r > w * 16 + ln)
                        sB[nb][r] = -INFINITY;
        }
        if (kt == qtA) {
            #pragma unroll
            for (int nb = 0; nb < 4; ++nb)
                #pragma unroll
                for (int r = 0; r < 4; ++r)
                    if ((nb >> 1) * 32 + g * 8 + (nb & 1) * 4 + r > w * 16 + ln)
                        sA[nb][r] = -INFINITY;
        }

        bf16x8 pfA[2], pfB[2];
        softmax_tile(sB, lB, pfB);
        if (actA) softmax_tile(sA, lA, pfA);

        __builtin_amdgcn_s_setprio(1);
        #pragma unroll
        for (int ks = 0; ks < 2; ++ks) {
            #pragma unroll
            for (int db = 0; db < 4; ++db) {
                const int d = db * 16 + ln;
                bf16x8 vf = *(const bf16x8*)(vb + d * 128 + (((ks * 4 + g) ^ sV) << 4));
                aoB[db] = __builtin_amdgcn_mfma_f32_16x16x32_bf16(pfB[ks], vf, aoB[db], 0, 0, 0);
                if (actA)
                    aoA[db] = __builtin_amdgcn_mfma_f32_16x16x32_bf16(pfA[ks], vf, aoA[db], 0, 0, 0);
            }
        }
        __builtin_amdgcn_s_setprio(0);
        buf ^= 1;
    }

    // epilogue: store UNNORMALIZED partials. l: reduce over the 4 g-groups.
    lA += __shfl_xor(lA, 16); lA += __shfl_xor(lA, 32);
    lB += __shfl_xor(lB, 16); lB += __shfl_xor(lB, 32);
    const int b = bh >> 4, h = bh & (NH - 1);
    if (l < 16) {   // g==0 lanes: one writer per q-row (row = ln)
        lp[(size_t)bh * SEQ + qtA * 64 + w * 16 + l] = lA;
        lp[(size_t)bh * SEQ + qtB * 64 + w * 16 + l] = lB;
    }
    #pragma unroll
    for (int r = 0; r < 4; ++r) {
        const size_t rowA = (size_t)(b * SEQ + qtA * 64 + w * 16 + g * 4 + r) * DMODEL + h * DH;
        const size_t rowB = (size_t)(b * SEQ + qtB * 64 + w * 16 + g * 4 + r) * DMODEL + h * DH;
        #pragma unroll
        for (int db = 0; db < 4; ++db) {
            Op[rowA + db * 16 + ln] = f2bf(aoA[db][r]);
            Op[rowB + db * 16 + ln] = f2bf(aoB[db][r]);
        }
    }
}

// ---------------------------------------------------------------------------
// combine: ob = (O0 + O1) / (l0 + l1), bf16 out. 8 elems/thread.
// ---------------------------------------------------------------------------
__global__ __launch_bounds__(256)
void combine(const unsigned short* __restrict__ O0,
             const unsigned short* __restrict__ O1,
             const float* __restrict__ l0, const float* __restrict__ l1,
             unsigned short* __restrict__ ob)
{
    const int i = blockIdx.x * 256 + threadIdx.x;      // 0..524287
    const int row = i >> 7;                            // 0..4095
    const int d0  = (i & 127) * 8;
    const int h   = d0 >> 6;
    const int b   = row >> 11, s = row & (SEQ - 1);
    const size_t li = ((size_t)b * NH + h) * SEQ + s;
    const float inv = 1.f / (l0[li] + l1[li]);
    const size_t off = (size_t)row * DMODEL + d0;
    u16x8 a = *(const u16x8*)(O0 + off);
    u16x8 c = *(const u16x8*)(O1 + off);
    u16x8 o;
    #pragma unroll
    for (int j = 0; j < 8; ++j)
        o[j] = f2bf((bf2f(a[j]) + bf2f(c[j])) * inv);
    *(u16x8*)(ob + off) = o;
}

// ---------------------------------------------------------------------------
extern "C" void kernel_launch(void* const* d_in, const int* in_sizes, int n_in,
                              void* d_out, int out_size, void* d_ws, size_t ws_size,
                              hipStream_t stream)
{
    const float* x  = (const float*)d_in[0];
    const float* wq = (const float*)d_in[1];
    const float* wo = (const float*)d_in[2];
    float* out = (float*)d_out;

    // ws layout (ushort units, 1M = 1<<20). Aliasing: O-partials overlay
    // xb/wqb which are dead after the QKV GEMM completes (same stream).
    const size_t M1 = 1u << 20;
    unsigned short* ws = (unsigned short*)d_ws;
    unsigned short* qb  = ws;                 // 4M  (live: QKV->attn)
    unsigned short* kb  = ws + 4 * M1;        // 4M
    unsigned short* vtb = ws + 8 * M1;        // 4M
    unsigned short* wob = ws + 12 * M1;       // 1M  (live: cast->outproj)
    unsigned short* xb  = ws + 13 * M1;       // 4M  (dead after QKV)
    unsigned short* wqb = ws + 17 * M1;       // 3M  (dead after QKV)
    unsigned short* Op0 = ws + 13 * M1;       // 4M  (alias xb)
    unsigned short* Op1 = ws + 17 * M1;       // 4M  (alias wqb + 1M)
    float* l0 = (float*)(ws + 21 * M1);       // 64K floats
    float* l1 = (float*)(ws + 21 * M1 + 256 * 1024);
    unsigned short* ob  = ws + 22 * M1;       // 4M  -> total 26M = 52MB

    cast_all<<<4096, 256, 0, stream>>>(x, wq, wo, xb, wqb, wob);

    dim3 g1(3072 / 128, 4096 / 128);
    gemm_bf16<128, 0><<<g1, 256, 0, stream>>>(xb, wqb, nullptr, qb, kb, vtb, 4096, 3072);

    dim3 g2(16, BATCH * NH, 2);
    attn_mfma<<<g2, 256, 0, stream>>>(qb, kb, vtb, Op0, Op1, l0, l1);

    combine<<<2048, 256, 0, stream>>>(Op0, Op1, l0, l1, ob);

    dim3 g3(1024 / 128, 4096 / 64);
    gemm_bf16<64, 1><<<g3, 256, 0, stream>>>(ob, wob, out, nullptr, nullptr, nullptr, 4096, 1024);
}